// Round 2
// baseline (1747.634 us; speedup 1.0000x reference)
//
#include <hip/hip_runtime.h>
#include <stdint.h>

#define HDIM  256
#define SEQ   2048
#define BATCH 64
#define NROW  (BATCH * SEQ)   // 131072 rows of x / xw

typedef __fp16 half2_t __attribute__((ext_vector_type(2)));

__device__ __forceinline__ float fdot2(uint32_t a, uint32_t b, float c) {
  return __builtin_amdgcn_fdot2(__builtin_bit_cast(half2_t, a),
                                __builtin_bit_cast(half2_t, b), c, false);
}

__device__ __forceinline__ uint32_t pack2_f16(float a, float b) {
  half2_t h = __builtin_amdgcn_cvt_pkrtz(a, b);  // v_cvt_pkrtz_f16_f32
  return __builtin_bit_cast(uint32_t, h);
}

// ---------------------------------------------------------------------------
// Phase 1: xw[r][h] = sum_i x[r][i] * W_ih[h][i], stored as f16.
// Thread t caches W_ih row t (256 f32 -> 128 packed f16) in VGPRs.
// x rows staged in LDS as f16 pairs; broadcast ds_read_b128 feeds v_dot2.
// ---------------------------------------------------------------------------
__global__ __launch_bounds__(256) void xw_gemm_kernel(
    const float* __restrict__ x, const float* __restrict__ W_ih,
    uint16_t* __restrict__ xw) {
  __shared__ uint32_t xrow[128];
  const int tid = threadIdx.x;

  uint32_t w[128];
  const float4* wr = (const float4*)(W_ih + tid * HDIM);
#pragma unroll
  for (int i = 0; i < 64; ++i) {
    float4 v = wr[i];
    w[2 * i]     = pack2_f16(v.x, v.y);
    w[2 * i + 1] = pack2_f16(v.z, v.w);
  }

  for (int r = blockIdx.x; r < NROW; r += gridDim.x) {
    if (tid < 128) {
      float2 v = ((const float2*)(x + (size_t)r * HDIM))[tid];
      xrow[tid] = pack2_f16(v.x, v.y);
    }
    __syncthreads();
    float a0 = 0.f, a1 = 0.f, a2 = 0.f, a3 = 0.f;
    const uint4* xp = (const uint4*)xrow;
#pragma unroll
    for (int c = 0; c < 32; ++c) {
      uint4 hv = xp[c];
      a0 = fdot2(w[4 * c + 0], hv.x, a0);
      a1 = fdot2(w[4 * c + 1], hv.y, a1);
      a2 = fdot2(w[4 * c + 2], hv.z, a2);
      a3 = fdot2(w[4 * c + 3], hv.w, a3);
    }
    float acc = (a0 + a1) + (a2 + a3);
    _Float16 hf = (_Float16)acc;
    xw[(size_t)r * HDIM + tid] = __builtin_bit_cast(uint16_t, hf);
    __syncthreads();
  }
}

// ---------------------------------------------------------------------------
// Phase 2: the serial scan. One workgroup per batch (64 wgs, latency-bound).
// Thread t owns W_hh row t in 128 packed-f16 VGPRs. h double-buffered in LDS
// (one __syncthreads per step). xw prefetched 2 steps ahead.
// ---------------------------------------------------------------------------
__global__ __launch_bounds__(256) void rnn_scan_kernel(
    const uint16_t* __restrict__ xw, const float* __restrict__ W_hh,
    float* __restrict__ out) {
  __shared__ _Float16 hbuf[2][HDIM];
  const int tid = threadIdx.x;
  const int b = blockIdx.x;

  uint32_t w[128];
  const float4* wr = (const float4*)(W_hh + tid * HDIM);
#pragma unroll
  for (int i = 0; i < 64; ++i) {
    float4 v = wr[i];
    w[2 * i]     = pack2_f16(v.x, v.y);
    w[2 * i + 1] = pack2_f16(v.z, v.w);
  }

  hbuf[0][tid] = (_Float16)0.f;

  const uint16_t* xwb = xw + (size_t)b * SEQ * HDIM;
  float* outb = out + (size_t)b * SEQ * HDIM;

  // xw prefetch pipeline, 2 deep
  uint16_t xq0 = xwb[tid];
  uint16_t xq1 = xwb[HDIM + tid];
  float last_h = 0.f;
  __syncthreads();

  for (int t = 0; t < SEQ; ++t) {
    int tp = t + 2;
    if (tp > SEQ - 1) tp = SEQ - 1;
    uint16_t xq2 = xwb[(size_t)tp * HDIM + tid];

    const int p = t & 1;
    const uint4* hp = (const uint4*)hbuf[p];
    float a0 = 0.f, a1 = 0.f, a2 = 0.f, a3 = 0.f;
#pragma unroll
    for (int c = 0; c < 32; ++c) {
      uint4 hv = hp[c];  // broadcast read: all lanes same address
      a0 = fdot2(w[4 * c + 0], hv.x, a0);
      a1 = fdot2(w[4 * c + 1], hv.y, a1);
      a2 = fdot2(w[4 * c + 2], hv.z, a2);
      a3 = fdot2(w[4 * c + 3], hv.w, a3);
    }
    float xv = (float)__builtin_bit_cast(_Float16, xq0);
    float pre = (a0 + a1) + (a2 + a3) + xv;

    // tanh(x) = 1 - 2/(exp(2x)+1); saturates gracefully at +-inf
    float e = __expf(2.0f * pre);
    float hval = 1.0f - 2.0f / (e + 1.0f);

    outb[(size_t)t * HDIM + tid] = hval;
    hbuf[1 - p][tid] = (_Float16)hval;
    last_h = hval;

    xq0 = xq1;
    xq1 = xq2;
    __syncthreads();
  }

  // h_n = last hidden state, appended after output in d_out
  out[(size_t)BATCH * SEQ * HDIM + (size_t)b * HDIM + tid] = last_h;
}

extern "C" void kernel_launch(void* const* d_in, const int* in_sizes, int n_in,
                              void* d_out, int out_size, void* d_ws,
                              size_t ws_size, hipStream_t stream) {
  const float* x    = (const float*)d_in[0];   // [64, 2048, 256] fp32
  const float* W_ih = (const float*)d_in[1];   // [256, 256] fp32
  const float* W_hh = (const float*)d_in[2];   // [256, 256] fp32
  float* out = (float*)d_out;                  // [64,2048,256] ++ [1,64,256]
  uint16_t* xw = (uint16_t*)d_ws;              // 131072*256 f16 = 67 MB

  hipLaunchKernelGGL(xw_gemm_kernel, dim3(512), dim3(256), 0, stream, x, W_ih,
                     xw);
  hipLaunchKernelGGL(rnn_scan_kernel, dim3(BATCH), dim3(256), 0, stream, xw,
                     W_hh, out);
}

// Round 3
// 1269.260 us; speedup vs baseline: 1.3769x; 1.3769x over previous
//
#include <hip/hip_runtime.h>
#include <stdint.h>

#define HDIM  256
#define SEQ   2048
#define BATCH 64

typedef __fp16 half2_t __attribute__((ext_vector_type(2)));
typedef __fp16 f16x8   __attribute__((ext_vector_type(8)));
typedef float  f32x4   __attribute__((ext_vector_type(4)));

__device__ __forceinline__ float fdot2(uint32_t a, uint32_t b, float c) {
  return __builtin_amdgcn_fdot2(__builtin_bit_cast(half2_t, a),
                                __builtin_bit_cast(half2_t, b), c, false);
}
__device__ __forceinline__ uint32_t pack2_f16(float a, float b) {
  half2_t h = __builtin_amdgcn_cvt_pkrtz(a, b);
  return __builtin_bit_cast(uint32_t, h);
}
// Pure-VALU cross-lane add: v += v_from(lane ^ mask), via DPP (no LDS unit).
template <int CTRL>
__device__ __forceinline__ float dpp_add(float v) {
  int y = __builtin_amdgcn_update_dpp(0, __builtin_bit_cast(int, v), CTRL,
                                      0xF, 0xF, true);
  return v + __builtin_bit_cast(float, y);
}

// ---------------------------------------------------------------------------
// Phase 1: xw = x @ W_ih^T via MFMA 16x16x32 f16.
// Wave w holds B-fragments (W_ih^T cols [64w,64w+64)) in 128 VGPRs.
// x staged f32->f16 in padded LDS; A-fragments read as b128 (distinct addrs).
// Grid 512 wgs x 4 row-blocks of 64 rows = 131072 rows.
// ---------------------------------------------------------------------------
#define LDK 264  // padded f16 row stride (264*2 B = 528 B; 528%128 != 0)

__global__ __launch_bounds__(256, 1) void xw_gemm_mfma(
    const float* __restrict__ x, const float* __restrict__ W_ih,
    _Float16* __restrict__ xw) {
  __shared__ _Float16 xsh[64 * LDK];  // 33 KB
  const int tid = threadIdx.x;
  const int wave = tid >> 6;
  const int lane = tid & 63;
  const int nl = lane & 15;  // tile col (n) / tile row (m) for A
  const int q = lane >> 4;   // quad

  // B-frag [k][n] = W_ih[n][k]; lane(nl,q) holds k = 32c+8q+j, n = base+nl.
  f16x8 Bf[4][8];
#pragma unroll
  for (int nt = 0; nt < 4; ++nt) {
    const float* wrow = W_ih + (size_t)(wave * 64 + nt * 16 + nl) * HDIM;
#pragma unroll
    for (int c = 0; c < 8; ++c) {
      const float* p = wrow + c * 32 + q * 8;
      f16x8 f;
#pragma unroll
      for (int j = 0; j < 8; ++j) f[j] = (__fp16)p[j];
      Bf[nt][c] = f;
    }
  }

  const size_t row0 = (size_t)blockIdx.x * 256;
  for (int blk = 0; blk < 4; ++blk) {
    const size_t rbase = row0 + (size_t)blk * 64;
    // coalesced load of 64x256 f32 block
    float4 xr[16];
    const float4* xg = (const float4*)(x + rbase * HDIM);
#pragma unroll
    for (int it = 0; it < 16; ++it) xr[it] = xg[(size_t)it * 256 + tid];
    __syncthreads();  // previous block's LDS reads complete
#pragma unroll
    for (int it = 0; it < 16; ++it) {
      int f = it * 1024 + tid * 4;
      int r = f >> 8, k = f & 255;
      uint2 v = make_uint2(pack2_f16(xr[it].x, xr[it].y),
                           pack2_f16(xr[it].z, xr[it].w));
      *(uint2*)(&xsh[r * LDK + k]) = v;
    }
    __syncthreads();

#pragma unroll
    for (int mt = 0; mt < 4; ++mt) {
      f32x4 acc[4] = {f32x4{0.f, 0.f, 0.f, 0.f}, f32x4{0.f, 0.f, 0.f, 0.f},
                      f32x4{0.f, 0.f, 0.f, 0.f}, f32x4{0.f, 0.f, 0.f, 0.f}};
#pragma unroll
      for (int c = 0; c < 8; ++c) {
        f16x8 A = *(const f16x8*)(&xsh[(mt * 16 + nl) * LDK + c * 32 + q * 8]);
#pragma unroll
        for (int nt = 0; nt < 4; ++nt)
          acc[nt] = __builtin_amdgcn_mfma_f32_16x16x32_f16(A, Bf[nt][c],
                                                           acc[nt], 0, 0, 0);
      }
      // D: row = q*4+r, col = nl (within tile)
#pragma unroll
      for (int nt = 0; nt < 4; ++nt)
#pragma unroll
        for (int r = 0; r < 4; ++r) {
          size_t row = rbase + mt * 16 + q * 4 + r;
          xw[row * HDIM + wave * 64 + nt * 16 + nl] = (_Float16)acc[nt][r];
        }
    }
  }
}

// ---------------------------------------------------------------------------
// Phase 2: serial scan, 1 batch/wg, 64 wgs. Split-K dot2:
// lane L: k-slice s=L&7 (chunks s,s+8,s+16,s+24 -> 4 conflict-free b128),
// 8 outputs (L&~7)+d. 8-lane reduce via DPP butterfly (XOR 1,2,7). Lane L
// keeps output o=L. One barrier/step, double-buffered h in LDS (f16).
// ---------------------------------------------------------------------------
__global__ __launch_bounds__(256, 1) void rnn_scan_kernel(
    const _Float16* __restrict__ xw, const float* __restrict__ W_hh,
    float* __restrict__ out) {
  __shared__ _Float16 hbuf[2][HDIM];
  const int tid = threadIdx.x;
  const int b = blockIdx.x;
  const int s = tid & 7;

  // weights: w[d][4i+p] = pack(W_hh[(tid&~7)+d][64i+8s+2p], ...+1)
  uint32_t w[8][16];
  {
    const int obase = tid & ~7;
#pragma unroll
    for (int d = 0; d < 8; ++d) {
      const float* wr = W_hh + (size_t)(obase + d) * HDIM;
#pragma unroll
      for (int i = 0; i < 4; ++i)
#pragma unroll
        for (int p2 = 0; p2 < 4; ++p2) {
          int k0 = 64 * i + 8 * s + 2 * p2;
          w[d][4 * i + p2] = pack2_f16(wr[k0], wr[k0 + 1]);
        }
    }
  }

  hbuf[0][tid] = (_Float16)0.f;

  const _Float16* xwb = xw + (size_t)b * SEQ * HDIM;
  float* outb = out + (size_t)b * SEQ * HDIM;

  _Float16 xq0 = xwb[tid];
  _Float16 xq1 = xwb[HDIM + tid];
  float last_h = 0.f;
  __syncthreads();

  for (int t = 0; t < SEQ; ++t) {
    int tp = t + 2;
    if (tp > SEQ - 1) tp = SEQ - 1;
    _Float16 xq2 = xwb[(size_t)tp * HDIM + tid];

    const int p = t & 1;
    const uint4* hp = (const uint4*)((const char*)hbuf[p] + 16 * s);
    uint4 c0 = hp[0];   // h[8s   .. 8s+7 ]
    uint4 c1 = hp[8];   // h[64+8s..     ]  (+128 B)
    uint4 c2 = hp[16];  // h[128+8s..    ]
    uint4 c3 = hp[24];  // h[192+8s..    ]

    float acc[8];
#pragma unroll
    for (int d = 0; d < 8; ++d) {
      float a = 0.f;
      a = fdot2(w[d][0], c0.x, a);
      a = fdot2(w[d][1], c0.y, a);
      a = fdot2(w[d][2], c0.z, a);
      a = fdot2(w[d][3], c0.w, a);
      a = fdot2(w[d][4], c1.x, a);
      a = fdot2(w[d][5], c1.y, a);
      a = fdot2(w[d][6], c1.z, a);
      a = fdot2(w[d][7], c1.w, a);
      a = fdot2(w[d][8], c2.x, a);
      a = fdot2(w[d][9], c2.y, a);
      a = fdot2(w[d][10], c2.z, a);
      a = fdot2(w[d][11], c2.w, a);
      a = fdot2(w[d][12], c3.x, a);
      a = fdot2(w[d][13], c3.y, a);
      a = fdot2(w[d][14], c3.z, a);
      a = fdot2(w[d][15], c3.w, a);
      acc[d] = a;
    }
    // 8-lane butterfly: every lane of the 8-group gets each output's sum
#pragma unroll
    for (int d = 0; d < 8; ++d) {
      acc[d] = dpp_add<0xB1>(acc[d]);   // quad_perm(1,0,3,2) = XOR 1
      acc[d] = dpp_add<0x4E>(acc[d]);   // quad_perm(2,3,0,1) = XOR 2
      acc[d] = dpp_add<0x141>(acc[d]);  // row_half_mirror    = XOR 7
    }
    // lane keeps d = s  ->  output o = (tid&~7)+s = tid
    float v0 = (s & 1) ? acc[1] : acc[0];
    float v1 = (s & 1) ? acc[3] : acc[2];
    float v2 = (s & 1) ? acc[5] : acc[4];
    float v3 = (s & 1) ? acc[7] : acc[6];
    float w0 = (s & 2) ? v1 : v0;
    float w1 = (s & 2) ? v3 : v2;
    float sum = (s & 4) ? w1 : w0;

    float pre = sum + (float)xq0;
    float e = __expf(2.0f * pre);
    float hval = 1.0f - 2.0f / (e + 1.0f);

    outb[(size_t)t * HDIM + tid] = hval;
    hbuf[1 - p][tid] = (_Float16)hval;
    last_h = hval;

    xq0 = xq1;
    xq1 = xq2;
    __syncthreads();
  }

  out[(size_t)BATCH * SEQ * HDIM + (size_t)b * HDIM + tid] = last_h;
}

extern "C" void kernel_launch(void* const* d_in, const int* in_sizes, int n_in,
                              void* d_out, int out_size, void* d_ws,
                              size_t ws_size, hipStream_t stream) {
  const float* x = (const float*)d_in[0];     // [64, 2048, 256] fp32
  const float* W_ih = (const float*)d_in[1];  // [256, 256] fp32
  const float* W_hh = (const float*)d_in[2];  // [256, 256] fp32
  float* out = (float*)d_out;                 // [64,2048,256] ++ [1,64,256]
  _Float16* xw = (_Float16*)d_ws;             // 131072*256 f16 = 67 MB

  hipLaunchKernelGGL(xw_gemm_mfma, dim3(512), dim3(256), 0, stream, x, W_ih,
                     xw);
  hipLaunchKernelGGL(rnn_scan_kernel, dim3(BATCH), dim3(256), 0, stream, xw,
                     W_hh, out);
}